// Round 8
// baseline (443.416 us; speedup 1.0000x reference)
//
#include <hip/hip_runtime.h>

#define NN 50000
#define NE 600000
#define DD 128
#define NG 64
#define PCH 48

typedef unsigned int uint;
typedef unsigned short ushort;
typedef __attribute__((ext_vector_type(8))) short short8;
typedef __attribute__((ext_vector_type(4))) float f4;

// ---------------- bf16 helpers ----------------

__device__ __forceinline__ float bf_lo(uint v) { return __uint_as_float(v << 16); }
__device__ __forceinline__ float bf_hi(uint v) { return __uint_as_float(v & 0xffff0000u); }
__device__ __forceinline__ float bf2f(ushort h) { return __uint_as_float((uint)h << 16); }
__device__ __forceinline__ ushort f2bf(float f) {
    uint u = __float_as_uint(f);
    uint r = (u + 0x7fffu + ((u >> 16) & 1u)) >> 16;   // round-nearest-even
    return (ushort)r;
}

// ---------------- setup (fused): hist + rank, W-pack, graph bounds ----------------
// blocks [0,586): degree histogram, 4 edges/thread (int4); rank[e] = the
// atomicAdd return so the CSR scatter is pure load/store (round-2 proven;
// atomicSub-in-scatter measured +9 us in round 6).
// blocks [586,610): pack W (split bf16 hi/lo into MFMA B-fragment layout).
// blocks [610,806): bound[g] = first node of graph g (batch sorted).
__global__ void k_setup(const int* __restrict__ dstv, int* __restrict__ deg,
                        int* __restrict__ rank,
                        const float* __restrict__ W1, const float* __restrict__ W2,
                        const float* __restrict__ W3, short* __restrict__ wpk,
                        const int* __restrict__ batch, int* __restrict__ bound) {
    if (blockIdx.x < 586) {
        int e0 = (blockIdx.x * 256 + threadIdx.x) * 4;
        if (e0 < NE) {                       // NE % 4 == 0 -> whole int4 in-bounds
            int4 d4 = *(const int4*)&dstv[e0];
            int4 r4;
            r4.x = atomicAdd(&deg[d4.x], 1);
            r4.y = atomicAdd(&deg[d4.y], 1);
            r4.z = atomicAdd(&deg[d4.z], 1);
            r4.w = atomicAdd(&deg[d4.w], 1);
            *(int4*)&rank[e0] = r4;
        }
    } else if (blockIdx.x < 610) {
        int u = (blockIdx.x - 586) * 256 + threadIdx.x;   // < 6144
        int layer = u >> 11, g = u & 2047;
        const float* W = (layer == 0) ? W1 : (layer == 1) ? W2 : W3;
        short* base = wpk + (size_t)layer * 32768;
        int nt = g >> 8, kk = (g >> 6) & 3, lane = g & 63;
        int k0 = kk * 32 + (lane >> 4) * 8;
        int n = nt * 16 + (lane & 15);
        #pragma unroll
        for (int j = 0; j < 8; ++j) {
            float w = W[(size_t)(k0 + j) * DD + n];
            ushort h = f2bf(w);
            base[g * 8 + j] = (short)h;
            base[16384 + g * 8 + j] = (short)f2bf(w - bf2f(h));
        }
    } else {
        int i = (blockIdx.x - 610) * 256 + threadIdx.x;
        if (i >= NN) return;
        int a = batch[i];
        if (i == 0) {
            for (int g = 0; g <= a; ++g) bound[g] = 0;
        } else {
            int b = batch[i - 1];
            for (int g = b + 1; g <= a; ++g) bound[g] = i;
        }
        if (i == NN - 1)
            for (int g = a + 1; g <= NG; ++g) bound[g] = NN;
    }
}

// Rows padded to multiples of 8 (pad cols -> zero row NN). rp is over PADDED
// sizes; dinv over true size (deg+1 incl self-loop).
__global__ void k_scan1(const int* __restrict__ deg, float* __restrict__ dinv,
                        int* __restrict__ rp, int* __restrict__ bsum) {
    __shared__ int s[256];
    int t = threadIdx.x, i = blockIdx.x * 256 + t;
    int ts = (i < NN) ? (deg[i] + 1) : 0;
    int vp = (i < NN) ? ((ts + 7) & ~7) : 0;
    if (i < NN) dinv[i] = rsqrtf((float)ts);
    s[t] = vp; __syncthreads();
    for (int off = 1; off < 256; off <<= 1) {
        int x = (t >= off) ? s[t - off] : 0;
        __syncthreads();
        s[t] += x;
        __syncthreads();
    }
    if (i < NN) rp[i] = s[t] - vp;          // exclusive (padded)
    if (t == 255) bsum[blockIdx.x] = s[255];
}

// fused scan2+scan3 + pad-slot fill + self-loop write + hsT zero-row init.
__global__ void k_scan23(int* __restrict__ rp, const int* __restrict__ bs,
                         const int* __restrict__ deg, ushort* __restrict__ col,
                         ushort* __restrict__ hsT) {
    __shared__ int s[256];
    int t = threadIdx.x;
    int v = (t < 196) ? bs[t] : 0;
    s[t] = v; __syncthreads();
    for (int off = 1; off < 256; off <<= 1) {
        int x = (t >= off) ? s[t - off] : 0;
        __syncthreads();
        s[t] += x;
        __syncthreads();
    }
    __shared__ int ps[256];
    ps[t] = s[t] - v;                        // exclusive
    __syncthreads();
    int add = ps[blockIdx.x];
    int i = blockIdx.x * 256 + t;
    if (i < NN) {
        int rpi = rp[i] + add;
        rp[i] = rpi;
        int ts = deg[i] + 1;
        int P = (ts + 7) & ~7;
        col[rpi] = (ushort)i;                // self-loop in slot 0, no atomic
        for (int j = ts; j < P; ++j) col[rpi + j] = (ushort)NN;  // pads -> zero row
    }
    if (blockIdx.x == 0) {
        if (t == 255) rp[NN] = s[255];       // total padded size
        if (t < 64) ((uint*)(hsT + (size_t)NN * DD))[t] = 0;   // zero row
    }
}

// XCD-localized CSR scatter (round-2 win: each dst-range's col slice stays in
// ONE XCD's L2 -> dense line fills, no cross-XCD writeback amplification).
// rank precomputed by k_setup -> pure load/store, no atomics.
__global__ __launch_bounds__(256) void k_scatter_xcd(const int* __restrict__ srcv,
                                                     const int* __restrict__ dstv,
                                                     const int* __restrict__ rank,
                                                     const int* __restrict__ rp,
                                                     ushort* __restrict__ col) {
    const int r8 = blockIdx.x & 7;
    const int chunk = blockIdx.x >> 3;
    const int lo = r8 * (NN / 8), hi = lo + (NN / 8);
    int e0 = chunk * 1024 + threadIdx.x * 4;
    if (e0 >= NE) return;                    // NE % 4 == 0: int4 loads in-bounds
    int4 d4 = *(const int4*)&dstv[e0];
    int4 s4 = *(const int4*)&srcv[e0];
    int4 k4 = *(const int4*)&rank[e0];
    const int* dp = (const int*)&d4;
    const int* sp = (const int*)&s4;
    const int* kp = (const int*)&k4;
    #pragma unroll
    for (int j = 0; j < 4; ++j) {
        int d = dp[j];
        if (d >= lo && d < hi)
            col[rp[d] + 1 + kp[j]] = (ushort)sp[j];   // slot 0 = self-loop
    }
}

// ---------------- MFMA GEMM ----------------
// out[r][c] = bf16( (X[r][:] @ W[:][c]) * dinv[r] )
// N split across blockIdx.y (2 halves of 64 cols); 32 KB LDS for W frags,
// reused post-barrier to stage C for coalesced float4 stores.
#define CST 72   // C-stage LDS row stride in shorts
template <int INF32>
__global__ __launch_bounds__(256) void k_gemm_mfma(const void* __restrict__ Xv,
                                                   const short* __restrict__ wpk,
                                                   const float* __restrict__ dinv,
                                                   ushort* __restrict__ out) {
    __shared__ short lds[16384];   // W: hi [0,8192), lo [8192,16384); C-stage reuse
    const int t = threadIdx.x;
    const int yb = blockIdx.y * 8192;
    #pragma unroll
    for (int m = 0; m < 4; ++m) {
        int idx = (m * 256 + t) * 8;
        *(float4*)&lds[idx] = *(const float4*)&wpk[yb + idx];
        *(float4*)&lds[8192 + idx] = *(const float4*)&wpk[16384 + yb + idx];
    }

    const int wv = t >> 6, lane = t & 63;
    const int quad = lane >> 4, l16 = lane & 15;
    const int r0 = blockIdx.x * 128 + wv * 32;

    short8 aH[2][4], aL[2][4];
    #pragma unroll
    for (int s = 0; s < 2; ++s) {
        int row = r0 + s * 16 + l16;
        #pragma unroll
        for (int kk = 0; kk < 4; ++kk) {
            int koff = kk * 32 + quad * 8;
            if (INF32) {
                float4 x0 = make_float4(0.f, 0.f, 0.f, 0.f), x1 = x0;
                if (row < NN) {
                    const float* p = (const float*)Xv + (size_t)row * DD + koff;
                    x0 = *(const float4*)p; x1 = *(const float4*)(p + 4);
                }
                float xs[8] = {x0.x, x0.y, x0.z, x0.w, x1.x, x1.y, x1.z, x1.w};
                short8 h, l;
                #pragma unroll
                for (int j = 0; j < 8; ++j) {
                    ushort hb = f2bf(xs[j]);
                    h[j] = (short)hb;
                    l[j] = (short)f2bf(xs[j] - bf2f(hb));
                }
                aH[s][kk] = h; aL[s][kk] = l;
            } else {
                short8 h = {0, 0, 0, 0, 0, 0, 0, 0};
                if (row < NN)
                    h = *(const short8*)((const ushort*)Xv + (size_t)row * DD + koff);
                aH[s][kk] = h;
            }
        }
    }
    __syncthreads();

    float dv[2][4];
    #pragma unroll
    for (int s = 0; s < 2; ++s)
        #pragma unroll
        for (int i = 0; i < 4; ++i) {
            int row = r0 + s * 16 + quad * 4 + i;
            dv[s][i] = (row < NN) ? dinv[row] : 0.f;
        }

    f4 acc[2][4];
    #pragma unroll
    for (int s = 0; s < 2; ++s)
        #pragma unroll
        for (int nt = 0; nt < 4; ++nt)
            acc[s][nt] = (f4){0.f, 0.f, 0.f, 0.f};

    #pragma unroll
    for (int nt = 0; nt < 4; ++nt) {
        #pragma unroll
        for (int kk = 0; kk < 4; ++kk) {
            int fi = ((nt * 4 + kk) * 64 + lane) * 8;
            short8 bh = *(const short8*)&lds[fi];
            short8 bl = *(const short8*)&lds[8192 + fi];
            acc[0][nt] = __builtin_amdgcn_mfma_f32_16x16x32_bf16(aH[0][kk], bh, acc[0][nt], 0, 0, 0);
            acc[0][nt] = __builtin_amdgcn_mfma_f32_16x16x32_bf16(aH[0][kk], bl, acc[0][nt], 0, 0, 0);
            acc[1][nt] = __builtin_amdgcn_mfma_f32_16x16x32_bf16(aH[1][kk], bh, acc[1][nt], 0, 0, 0);
            acc[1][nt] = __builtin_amdgcn_mfma_f32_16x16x32_bf16(aH[1][kk], bl, acc[1][nt], 0, 0, 0);
            if (INF32) {
                acc[0][nt] = __builtin_amdgcn_mfma_f32_16x16x32_bf16(aL[0][kk], bh, acc[0][nt], 0, 0, 0);
                acc[1][nt] = __builtin_amdgcn_mfma_f32_16x16x32_bf16(aL[1][kk], bh, acc[1][nt], 0, 0, 0);
            }
        }
    }

    __syncthreads();   // reuse LDS for C stage
    #pragma unroll
    for (int s = 0; s < 2; ++s) {
        int lr = wv * 32 + s * 16 + quad * 4;
        #pragma unroll
        for (int nt = 0; nt < 4; ++nt)
            #pragma unroll
            for (int i = 0; i < 4; ++i)
                lds[(lr + i) * CST + nt * 16 + l16] = (short)f2bf(acc[s][nt][i] * dv[s][i]);
    }
    __syncthreads();

    int row = t >> 1, half = t & 1;
    int grow = blockIdx.x * 128 + row;
    if (grow < NN) {
        #pragma unroll
        for (int j = 0; j < 4; ++j) {
            float4 v = *(float4*)&lds[row * CST + half * 32 + j * 8];
            *(float4*)&out[(size_t)grow * DD + blockIdx.y * 64 + half * 32 + j * 8] = v;
        }
    }
}

// ---------------- aggregation ----------------
// out[i] = maybe_relu( dinv[i] * sum_{p in row i} hs[col[p]] + bias )
// Round-2 row-major streaming version -- BEST MEASURED (~31 us/layer).
// NOTE (rounds 4/5/7): all L2-residency variants (planar / quarter-phase)
// lose structurally: on a random graph every XCD touches the whole 12.8 MB
// table, so phase-resident schemes pay working-set x 8-XCD replication
// (~102 MB/layer TCC fill, measured) vs ~60-75 MB for plain streaming at the
// same ~2 TB/s fill rate. Do not revisit.
// Wave per node, lane = 1 dword (2 dims); one aligned 16 B col load / 8 nbrs.
template <int RELU, int OUTF32>
__global__ __launch_bounds__(256) void k_agg(const ushort* __restrict__ hs,
                                             const ushort* __restrict__ col,
                                             const int* __restrict__ rp,
                                             const float* __restrict__ dinv,
                                             const float* __restrict__ bias,
                                             void* __restrict__ outv) {
    int w = threadIdx.x >> 6, lane = threadIdx.x & 63;
    int i = blockIdx.x * 4 + w;
    if (i >= NN) return;
    int p0 = rp[i], p1 = rp[i + 1];
    int d = lane * 2;
    const ushort* hsd = hs + d;
    float x0 = 0.f, y0 = 0.f, x1 = 0.f, y1 = 0.f;
    float x2 = 0.f, y2 = 0.f, x3 = 0.f, y3 = 0.f;
    for (int p = p0; p < p1; p += 8) {
        short8 cv = *(const short8*)&col[p];
        int c0 = (ushort)cv[0], c1 = (ushort)cv[1], c2 = (ushort)cv[2], c3 = (ushort)cv[3];
        int c4 = (ushort)cv[4], c5 = (ushort)cv[5], c6 = (ushort)cv[6], c7 = (ushort)cv[7];
        uint v0 = *(const uint*)(hsd + (size_t)c0 * DD);
        uint v1 = *(const uint*)(hsd + (size_t)c1 * DD);
        uint v2 = *(const uint*)(hsd + (size_t)c2 * DD);
        uint v3 = *(const uint*)(hsd + (size_t)c3 * DD);
        uint v4 = *(const uint*)(hsd + (size_t)c4 * DD);
        uint v5 = *(const uint*)(hsd + (size_t)c5 * DD);
        uint v6 = *(const uint*)(hsd + (size_t)c6 * DD);
        uint v7 = *(const uint*)(hsd + (size_t)c7 * DD);
        x0 += bf_lo(v0); y0 += bf_hi(v0); x1 += bf_lo(v1); y1 += bf_hi(v1);
        x2 += bf_lo(v2); y2 += bf_hi(v2); x3 += bf_lo(v3); y3 += bf_hi(v3);
        x0 += bf_lo(v4); y0 += bf_hi(v4); x1 += bf_lo(v5); y1 += bf_hi(v5);
        x2 += bf_lo(v6); y2 += bf_hi(v6); x3 += bf_lo(v7); y3 += bf_hi(v7);
    }
    float ax = (x0 + x1) + (x2 + x3);
    float ay = (y0 + y1) + (y2 + y3);
    float s = dinv[i];
    float2 bb = *(const float2*)(bias + d);
    float ox = fmaf(s, ax, bb.x), oy = fmaf(s, ay, bb.y);
    if (RELU) { ox = fmaxf(ox, 0.f); oy = fmaxf(oy, 0.f); }
    if (OUTF32) {
        *(float2*)((float*)outv + (size_t)i * DD + d) = make_float2(ox, oy);
    } else {
        ushort2 o; o.x = f2bf(ox); o.y = f2bf(oy);
        *(ushort2*)((ushort*)outv + (size_t)i * DD + d) = o;
    }
}

// ---------------- pool (+ fused final) ----------------
// Segmented mean via graph boundaries (batch sorted). Grid = 64 graphs x 48
// chunks; 256 threads stream contiguous rows (branchless, no batch loads),
// LDS-fold the 2 row-halves, one atomicAdd per (dim, chunk). Last block
// (device-scope ticket, validated round 5) divides sums by counts -> out.
__global__ __launch_bounds__(256) void k_pool_seg(const float* __restrict__ F,
                                                  const int* __restrict__ bound,
                                                  float* __restrict__ sums,
                                                  int* __restrict__ done,
                                                  float* __restrict__ out) {
    int g = blockIdx.x / PCH, c = blockIdx.x - g * PCH;
    int lo = bound[g], len = bound[g + 1] - lo;
    int cl = lo + (len * c) / PCH, ch = lo + (len * (c + 1)) / PCH;
    int t = threadIdx.x, d = t & 127, h = t >> 7;
    float acc = 0.f;
    for (int r = cl + h; r < ch; r += 2)
        acc += F[(size_t)r * DD + d];
    __shared__ float s[256];
    s[t] = acc; __syncthreads();
    if (t < 128) {
        float v = s[t] + s[t + 128];
        atomicAdd(&sums[g * DD + d], v);
    }

    __threadfence();
    __shared__ int lastblk;
    if (t == 0) lastblk = (atomicAdd(done, 1) == (int)gridDim.x - 1);
    __syncthreads();
    if (lastblk) {
        for (int i = t; i < NG * DD; i += 256) {
            float sv = __hip_atomic_load(&sums[i], __ATOMIC_RELAXED, __HIP_MEMORY_SCOPE_AGENT);
            float cv = (float)(bound[(i >> 7) + 1] - bound[i >> 7]);
            out[i] = sv / fmaxf(cv, 1.f);
        }
    }
}

// ---------------- launch ----------------

extern "C" void kernel_launch(void* const* d_in, const int* in_sizes, int n_in,
                              void* d_out, int out_size, void* d_ws, size_t ws_size,
                              hipStream_t stream) {
    (void)in_sizes; (void)n_in; (void)out_size; (void)ws_size;
    const float* x  = (const float*)d_in[0];
    const int*   ei = (const int*)d_in[1];
    const int*   bt = (const int*)d_in[2];
    const float* W1 = (const float*)d_in[3];
    const float* b1 = (const float*)d_in[4];
    const float* W2 = (const float*)d_in[5];
    const float* b2 = (const float*)d_in[6];
    const float* W3 = (const float*)d_in[7];
    const float* b3 = (const float*)d_in[8];
    float* out = (float*)d_out;
    char* ws = (char*)d_ws;

    size_t o = 0;
    auto alloc = [&](size_t bytes) { size_t r = o; o = (o + bytes + 511) & ~(size_t)511; return r; };
    // zeroed region: deg + pool sums + done (one memset)
    int*    deg  = (int*)(ws + alloc((size_t)NN * 4));
    float*  pool = (float*)(ws + alloc((size_t)(NG * DD + 1) * 4));
    int*    done = (int*)(pool + NG * DD);
    size_t zbytes = o;
    float*  dinv = (float*)(ws + alloc((size_t)NN * 4));
    int*    rp   = (int*)(ws + alloc((size_t)(NN + 1) * 4));
    int*    bs   = (int*)(ws + alloc(256 * 4));
    int*    bnd  = (int*)(ws + alloc((size_t)(NG + 1) * 4));
    int*    rank = (int*)(ws + alloc((size_t)NE * 4));
    ushort* col  = (ushort*)(ws + alloc((size_t)(NE + 8 * NN) * 2));  // padded CSR
    short*  wpk  = (short*)(ws + alloc((size_t)3 * 32768 * 2));
    ushort* hsT  = (ushort*)(ws + alloc((size_t)(NN + 1) * DD * 2)); // +1 zero row
    ushort* hsA  = (ushort*)(ws + alloc((size_t)NN * DD * 2));
    float*  F    = (float*)(ws + alloc((size_t)NN * DD * 4));

    const int* srcv = ei;        // edge_index[0]
    const int* dstv = ei + NE;   // edge_index[1]

    hipMemsetAsync(ws, 0, zbytes, stream);

    k_setup<<<806, 256, 0, stream>>>(dstv, deg, rank, W1, W2, W3, wpk, bt, bnd);
    k_scan1<<<196, 256, 0, stream>>>(deg, dinv, rp, bs);
    k_scan23<<<196, 256, 0, stream>>>(rp, bs, deg, col, hsT);
    k_scatter_xcd<<<((NE + 1023) / 1024) * 8, 256, 0, stream>>>(srcv, dstv, rank, rp, col);

    const dim3 gG((NN + 127) / 128, 2);   // 391 x 2
    k_gemm_mfma<1><<<gG, 256, 0, stream>>>(x, wpk, dinv, hsT);
    k_agg<1, 0><<<12500, 256, 0, stream>>>(hsT, col, rp, dinv, b1, hsA);
    k_gemm_mfma<0><<<gG, 256, 0, stream>>>(hsA, wpk + 32768, dinv, hsT);
    k_agg<1, 0><<<12500, 256, 0, stream>>>(hsT, col, rp, dinv, b2, hsA);
    k_gemm_mfma<0><<<gG, 256, 0, stream>>>(hsA, wpk + 65536, dinv, hsT);
    k_agg<0, 1><<<12500, 256, 0, stream>>>(hsT, col, rp, dinv, b3, F);

    k_pool_seg<<<NG * PCH, 256, 0, stream>>>(F, bnd, pool, done, out);
}

// Round 9
// 258.779 us; speedup vs baseline: 1.7135x; 1.7135x over previous
//
#include <hip/hip_runtime.h>

#define NN 50000
#define NE 600000
#define DD 128
#define NG 64
#define PCH 16

typedef unsigned int uint;
typedef unsigned short ushort;
typedef __attribute__((ext_vector_type(8))) short short8;
typedef __attribute__((ext_vector_type(4))) float f4;

// ---------------- bf16 helpers ----------------

__device__ __forceinline__ float bf_lo(uint v) { return __uint_as_float(v << 16); }
__device__ __forceinline__ float bf_hi(uint v) { return __uint_as_float(v & 0xffff0000u); }
__device__ __forceinline__ float bf2f(ushort h) { return __uint_as_float((uint)h << 16); }
__device__ __forceinline__ ushort f2bf(float f) {
    uint u = __float_as_uint(f);
    uint r = (u + 0x7fffu + ((u >> 16) & 1u)) >> 16;   // round-nearest-even
    return (ushort)r;
}

// ---------------- setup (fused): hist + rank, W-pack, graph bounds ----------------
// blocks [0,586): degree histogram, 4 edges/thread (int4); rank[e] = the
// atomicAdd return so the CSR scatter is pure load/store (round-2 proven;
// atomicSub-in-scatter measured +9 us in round 6).
// blocks [586,610): pack W (split bf16 hi/lo into MFMA B-fragment layout).
// blocks [610,806): bound[g] = first node of graph g (batch sorted).
__global__ void k_setup(const int* __restrict__ dstv, int* __restrict__ deg,
                        int* __restrict__ rank,
                        const float* __restrict__ W1, const float* __restrict__ W2,
                        const float* __restrict__ W3, short* __restrict__ wpk,
                        const int* __restrict__ batch, int* __restrict__ bound) {
    if (blockIdx.x < 586) {
        int e0 = (blockIdx.x * 256 + threadIdx.x) * 4;
        if (e0 < NE) {                       // NE % 4 == 0 -> whole int4 in-bounds
            int4 d4 = *(const int4*)&dstv[e0];
            int4 r4;
            r4.x = atomicAdd(&deg[d4.x], 1);
            r4.y = atomicAdd(&deg[d4.y], 1);
            r4.z = atomicAdd(&deg[d4.z], 1);
            r4.w = atomicAdd(&deg[d4.w], 1);
            *(int4*)&rank[e0] = r4;
        }
    } else if (blockIdx.x < 610) {
        int u = (blockIdx.x - 586) * 256 + threadIdx.x;   // < 6144
        int layer = u >> 11, g = u & 2047;
        const float* W = (layer == 0) ? W1 : (layer == 1) ? W2 : W3;
        short* base = wpk + (size_t)layer * 32768;
        int nt = g >> 8, kk = (g >> 6) & 3, lane = g & 63;
        int k0 = kk * 32 + (lane >> 4) * 8;
        int n = nt * 16 + (lane & 15);
        #pragma unroll
        for (int j = 0; j < 8; ++j) {
            float w = W[(size_t)(k0 + j) * DD + n];
            ushort h = f2bf(w);
            base[g * 8 + j] = (short)h;
            base[16384 + g * 8 + j] = (short)f2bf(w - bf2f(h));
        }
    } else {
        int i = (blockIdx.x - 610) * 256 + threadIdx.x;
        if (i >= NN) return;
        int a = batch[i];
        if (i == 0) {
            for (int g = 0; g <= a; ++g) bound[g] = 0;
        } else {
            int b = batch[i - 1];
            for (int g = b + 1; g <= a; ++g) bound[g] = i;
        }
        if (i == NN - 1)
            for (int g = a + 1; g <= NG; ++g) bound[g] = NN;
    }
}

// Rows padded to multiples of 8 (pad cols -> zero row NN). rp is over PADDED
// sizes; dinv over true size (deg+1 incl self-loop).
__global__ void k_scan1(const int* __restrict__ deg, float* __restrict__ dinv,
                        int* __restrict__ rp, int* __restrict__ bsum) {
    __shared__ int s[256];
    int t = threadIdx.x, i = blockIdx.x * 256 + t;
    int ts = (i < NN) ? (deg[i] + 1) : 0;
    int vp = (i < NN) ? ((ts + 7) & ~7) : 0;
    if (i < NN) dinv[i] = rsqrtf((float)ts);
    s[t] = vp; __syncthreads();
    for (int off = 1; off < 256; off <<= 1) {
        int x = (t >= off) ? s[t - off] : 0;
        __syncthreads();
        s[t] += x;
        __syncthreads();
    }
    if (i < NN) rp[i] = s[t] - vp;          // exclusive (padded)
    if (t == 255) bsum[blockIdx.x] = s[255];
}

// fused scan2+scan3 + pad-slot fill + self-loop write + hsT zero-row init.
__global__ void k_scan23(int* __restrict__ rp, const int* __restrict__ bs,
                         const int* __restrict__ deg, ushort* __restrict__ col,
                         ushort* __restrict__ hsT) {
    __shared__ int s[256];
    int t = threadIdx.x;
    int v = (t < 196) ? bs[t] : 0;
    s[t] = v; __syncthreads();
    for (int off = 1; off < 256; off <<= 1) {
        int x = (t >= off) ? s[t - off] : 0;
        __syncthreads();
        s[t] += x;
        __syncthreads();
    }
    __shared__ int ps[256];
    ps[t] = s[t] - v;                        // exclusive
    __syncthreads();
    int add = ps[blockIdx.x];
    int i = blockIdx.x * 256 + t;
    if (i < NN) {
        int rpi = rp[i] + add;
        rp[i] = rpi;
        int ts = deg[i] + 1;
        int P = (ts + 7) & ~7;
        col[rpi] = (ushort)i;                // self-loop in slot 0, no atomic
        for (int j = ts; j < P; ++j) col[rpi + j] = (ushort)NN;  // pads -> zero row
    }
    if (blockIdx.x == 0) {
        if (t == 255) rp[NN] = s[255];       // total padded size
        if (t < 64) ((uint*)(hsT + (size_t)NN * DD))[t] = 0;   // zero row
    }
}

// XCD-localized CSR scatter (round-2 win: each dst-range's col slice stays in
// ONE XCD's L2 -> dense line fills, no cross-XCD writeback amplification).
// rank precomputed by k_setup -> pure load/store, no atomics.
__global__ __launch_bounds__(256) void k_scatter_xcd(const int* __restrict__ srcv,
                                                     const int* __restrict__ dstv,
                                                     const int* __restrict__ rank,
                                                     const int* __restrict__ rp,
                                                     ushort* __restrict__ col) {
    const int r8 = blockIdx.x & 7;
    const int chunk = blockIdx.x >> 3;
    const int lo = r8 * (NN / 8), hi = lo + (NN / 8);
    int e0 = chunk * 1024 + threadIdx.x * 4;
    if (e0 >= NE) return;                    // NE % 4 == 0: int4 loads in-bounds
    int4 d4 = *(const int4*)&dstv[e0];
    int4 s4 = *(const int4*)&srcv[e0];
    int4 k4 = *(const int4*)&rank[e0];
    const int* dp = (const int*)&d4;
    const int* sp = (const int*)&s4;
    const int* kp = (const int*)&k4;
    #pragma unroll
    for (int j = 0; j < 4; ++j) {
        int d = dp[j];
        if (d >= lo && d < hi)
            col[rp[d] + 1 + kp[j]] = (ushort)sp[j];   // slot 0 = self-loop
    }
}

// ---------------- MFMA GEMM ----------------
// out[r][c] = bf16( (X[r][:] @ W[:][c]) * dinv[r] )
// N split across blockIdx.y (2 halves of 64 cols); 32 KB LDS for W frags,
// reused post-barrier to stage C for coalesced float4 stores.
#define CST 72   // C-stage LDS row stride in shorts
template <int INF32>
__global__ __launch_bounds__(256) void k_gemm_mfma(const void* __restrict__ Xv,
                                                   const short* __restrict__ wpk,
                                                   const float* __restrict__ dinv,
                                                   ushort* __restrict__ out) {
    __shared__ short lds[16384];   // W: hi [0,8192), lo [8192,16384); C-stage reuse
    const int t = threadIdx.x;
    const int yb = blockIdx.y * 8192;
    #pragma unroll
    for (int m = 0; m < 4; ++m) {
        int idx = (m * 256 + t) * 8;
        *(float4*)&lds[idx] = *(const float4*)&wpk[yb + idx];
        *(float4*)&lds[8192 + idx] = *(const float4*)&wpk[16384 + yb + idx];
    }

    const int wv = t >> 6, lane = t & 63;
    const int quad = lane >> 4, l16 = lane & 15;
    const int r0 = blockIdx.x * 128 + wv * 32;

    short8 aH[2][4], aL[2][4];
    #pragma unroll
    for (int s = 0; s < 2; ++s) {
        int row = r0 + s * 16 + l16;
        #pragma unroll
        for (int kk = 0; kk < 4; ++kk) {
            int koff = kk * 32 + quad * 8;
            if (INF32) {
                float4 x0 = make_float4(0.f, 0.f, 0.f, 0.f), x1 = x0;
                if (row < NN) {
                    const float* p = (const float*)Xv + (size_t)row * DD + koff;
                    x0 = *(const float4*)p; x1 = *(const float4*)(p + 4);
                }
                float xs[8] = {x0.x, x0.y, x0.z, x0.w, x1.x, x1.y, x1.z, x1.w};
                short8 h, l;
                #pragma unroll
                for (int j = 0; j < 8; ++j) {
                    ushort hb = f2bf(xs[j]);
                    h[j] = (short)hb;
                    l[j] = (short)f2bf(xs[j] - bf2f(hb));
                }
                aH[s][kk] = h; aL[s][kk] = l;
            } else {
                short8 h = {0, 0, 0, 0, 0, 0, 0, 0};
                if (row < NN)
                    h = *(const short8*)((const ushort*)Xv + (size_t)row * DD + koff);
                aH[s][kk] = h;
            }
        }
    }
    __syncthreads();

    float dv[2][4];
    #pragma unroll
    for (int s = 0; s < 2; ++s)
        #pragma unroll
        for (int i = 0; i < 4; ++i) {
            int row = r0 + s * 16 + quad * 4 + i;
            dv[s][i] = (row < NN) ? dinv[row] : 0.f;
        }

    f4 acc[2][4];
    #pragma unroll
    for (int s = 0; s < 2; ++s)
        #pragma unroll
        for (int nt = 0; nt < 4; ++nt)
            acc[s][nt] = (f4){0.f, 0.f, 0.f, 0.f};

    #pragma unroll
    for (int nt = 0; nt < 4; ++nt) {
        #pragma unroll
        for (int kk = 0; kk < 4; ++kk) {
            int fi = ((nt * 4 + kk) * 64 + lane) * 8;
            short8 bh = *(const short8*)&lds[fi];
            short8 bl = *(const short8*)&lds[8192 + fi];
            acc[0][nt] = __builtin_amdgcn_mfma_f32_16x16x32_bf16(aH[0][kk], bh, acc[0][nt], 0, 0, 0);
            acc[0][nt] = __builtin_amdgcn_mfma_f32_16x16x32_bf16(aH[0][kk], bl, acc[0][nt], 0, 0, 0);
            acc[1][nt] = __builtin_amdgcn_mfma_f32_16x16x32_bf16(aH[1][kk], bh, acc[1][nt], 0, 0, 0);
            acc[1][nt] = __builtin_amdgcn_mfma_f32_16x16x32_bf16(aH[1][kk], bl, acc[1][nt], 0, 0, 0);
            if (INF32) {
                acc[0][nt] = __builtin_amdgcn_mfma_f32_16x16x32_bf16(aL[0][kk], bh, acc[0][nt], 0, 0, 0);
                acc[1][nt] = __builtin_amdgcn_mfma_f32_16x16x32_bf16(aL[1][kk], bh, acc[1][nt], 0, 0, 0);
            }
        }
    }

    __syncthreads();   // reuse LDS for C stage
    #pragma unroll
    for (int s = 0; s < 2; ++s) {
        int lr = wv * 32 + s * 16 + quad * 4;
        #pragma unroll
        for (int nt = 0; nt < 4; ++nt)
            #pragma unroll
            for (int i = 0; i < 4; ++i)
                lds[(lr + i) * CST + nt * 16 + l16] = (short)f2bf(acc[s][nt][i] * dv[s][i]);
    }
    __syncthreads();

    int row = t >> 1, half = t & 1;
    int grow = blockIdx.x * 128 + row;
    if (grow < NN) {
        #pragma unroll
        for (int j = 0; j < 4; ++j) {
            float4 v = *(float4*)&lds[row * CST + half * 32 + j * 8];
            *(float4*)&out[(size_t)grow * DD + blockIdx.y * 64 + half * 32 + j * 8] = v;
        }
    }
}

// ---------------- aggregation ----------------
// out[i] = maybe_relu( dinv[i] * sum_{p in row i} hs[col[p]] + bias )
// Round-2 row-major streaming version -- BEST MEASURED (~31 us/layer).
// NOTE (rounds 4/5/7): all L2-residency variants (planar / quarter-phase)
// lose structurally: on a random graph every XCD touches the whole 12.8 MB
// table, so phase-resident schemes pay working-set x 8-XCD replication
// (~102 MB/layer TCC fill, measured) vs ~60-75 MB for plain streaming at the
// same ~2 TB/s fill rate. Do not revisit.
// Wave per node, lane = 1 dword (2 dims); one aligned 16 B col load / 8 nbrs.
template <int RELU, int OUTF32>
__global__ __launch_bounds__(256) void k_agg(const ushort* __restrict__ hs,
                                             const ushort* __restrict__ col,
                                             const int* __restrict__ rp,
                                             const float* __restrict__ dinv,
                                             const float* __restrict__ bias,
                                             void* __restrict__ outv) {
    int w = threadIdx.x >> 6, lane = threadIdx.x & 63;
    int i = blockIdx.x * 4 + w;
    if (i >= NN) return;
    int p0 = rp[i], p1 = rp[i + 1];
    int d = lane * 2;
    const ushort* hsd = hs + d;
    float x0 = 0.f, y0 = 0.f, x1 = 0.f, y1 = 0.f;
    float x2 = 0.f, y2 = 0.f, x3 = 0.f, y3 = 0.f;
    for (int p = p0; p < p1; p += 8) {
        short8 cv = *(const short8*)&col[p];
        int c0 = (ushort)cv[0], c1 = (ushort)cv[1], c2 = (ushort)cv[2], c3 = (ushort)cv[3];
        int c4 = (ushort)cv[4], c5 = (ushort)cv[5], c6 = (ushort)cv[6], c7 = (ushort)cv[7];
        uint v0 = *(const uint*)(hsd + (size_t)c0 * DD);
        uint v1 = *(const uint*)(hsd + (size_t)c1 * DD);
        uint v2 = *(const uint*)(hsd + (size_t)c2 * DD);
        uint v3 = *(const uint*)(hsd + (size_t)c3 * DD);
        uint v4 = *(const uint*)(hsd + (size_t)c4 * DD);
        uint v5 = *(const uint*)(hsd + (size_t)c5 * DD);
        uint v6 = *(const uint*)(hsd + (size_t)c6 * DD);
        uint v7 = *(const uint*)(hsd + (size_t)c7 * DD);
        x0 += bf_lo(v0); y0 += bf_hi(v0); x1 += bf_lo(v1); y1 += bf_hi(v1);
        x2 += bf_lo(v2); y2 += bf_hi(v2); x3 += bf_lo(v3); y3 += bf_hi(v3);
        x0 += bf_lo(v4); y0 += bf_hi(v4); x1 += bf_lo(v5); y1 += bf_hi(v5);
        x2 += bf_lo(v6); y2 += bf_hi(v6); x3 += bf_lo(v7); y3 += bf_hi(v7);
    }
    float ax = (x0 + x1) + (x2 + x3);
    float ay = (y0 + y1) + (y2 + y3);
    float s = dinv[i];
    float2 bb = *(const float2*)(bias + d);
    float ox = fmaf(s, ax, bb.x), oy = fmaf(s, ay, bb.y);
    if (RELU) { ox = fmaxf(ox, 0.f); oy = fmaxf(oy, 0.f); }
    if (OUTF32) {
        *(float2*)((float*)outv + (size_t)i * DD + d) = make_float2(ox, oy);
    } else {
        ushort2 o; o.x = f2bf(ox); o.y = f2bf(oy);
        *(ushort2*)((ushort*)outv + (size_t)i * DD + d) = o;
    }
}

// ---------------- pool ----------------
// Segmented mean via graph boundaries (batch sorted). Grid = 64 graphs x 16
// chunks; 256 threads stream contiguous rows (branchless, no batch loads),
// LDS-fold the 2 row-halves, one atomicAdd per (dim, chunk).
// NOTE (round 8): do NOT fuse the final divide via a last-block-done ticket.
// The required per-block __threadfence() (device-scope release) forces L2
// writebacks on non-coherent-XCD gfx950; 3072 fences measured 199.6 us with
// all pipes idle. A separate 2 us kernel launch is the cheap ordering point.
__global__ __launch_bounds__(256) void k_pool_seg(const float* __restrict__ F,
                                                  const int* __restrict__ bound,
                                                  float* __restrict__ sums) {
    int g = blockIdx.x >> 4, c = blockIdx.x & (PCH - 1);
    int lo = bound[g], len = bound[g + 1] - lo;
    int cl = lo + (len * c) / PCH, ch = lo + (len * (c + 1)) / PCH;
    int t = threadIdx.x, d = t & 127, h = t >> 7;
    float acc = 0.f;
    for (int r = cl + h; r < ch; r += 2)
        acc += F[(size_t)r * DD + d];
    __shared__ float s[256];
    s[t] = acc; __syncthreads();
    if (t < 128) {
        float v = s[t] + s[t + 128];
        atomicAdd(&sums[g * DD + d], v);
    }
}

__global__ void k_final(const float* __restrict__ sums, const int* __restrict__ bound,
                        float* __restrict__ out) {
    int i = blockIdx.x * 256 + threadIdx.x;  // < NG*DD = 8192
    int g = i >> 7;
    float c = (float)(bound[g + 1] - bound[g]);
    out[i] = sums[i] / fmaxf(c, 1.f);
}

// ---------------- launch ----------------

extern "C" void kernel_launch(void* const* d_in, const int* in_sizes, int n_in,
                              void* d_out, int out_size, void* d_ws, size_t ws_size,
                              hipStream_t stream) {
    (void)in_sizes; (void)n_in; (void)out_size; (void)ws_size;
    const float* x  = (const float*)d_in[0];
    const int*   ei = (const int*)d_in[1];
    const int*   bt = (const int*)d_in[2];
    const float* W1 = (const float*)d_in[3];
    const float* b1 = (const float*)d_in[4];
    const float* W2 = (const float*)d_in[5];
    const float* b2 = (const float*)d_in[6];
    const float* W3 = (const float*)d_in[7];
    const float* b3 = (const float*)d_in[8];
    float* out = (float*)d_out;
    char* ws = (char*)d_ws;

    size_t o = 0;
    auto alloc = [&](size_t bytes) { size_t r = o; o = (o + bytes + 511) & ~(size_t)511; return r; };
    // zeroed region: deg + pool sums (one memset)
    int*    deg  = (int*)(ws + alloc((size_t)NN * 4));
    float*  pool = (float*)(ws + alloc((size_t)(NG * DD) * 4));
    size_t zbytes = o;
    float*  dinv = (float*)(ws + alloc((size_t)NN * 4));
    int*    rp   = (int*)(ws + alloc((size_t)(NN + 1) * 4));
    int*    bs   = (int*)(ws + alloc(256 * 4));
    int*    bnd  = (int*)(ws + alloc((size_t)(NG + 1) * 4));
    int*    rank = (int*)(ws + alloc((size_t)NE * 4));
    ushort* col  = (ushort*)(ws + alloc((size_t)(NE + 8 * NN) * 2));  // padded CSR
    short*  wpk  = (short*)(ws + alloc((size_t)3 * 32768 * 2));
    ushort* hsT  = (ushort*)(ws + alloc((size_t)(NN + 1) * DD * 2)); // +1 zero row
    ushort* hsA  = (ushort*)(ws + alloc((size_t)NN * DD * 2));
    float*  F    = (float*)(ws + alloc((size_t)NN * DD * 4));

    const int* srcv = ei;        // edge_index[0]
    const int* dstv = ei + NE;   // edge_index[1]

    hipMemsetAsync(ws, 0, zbytes, stream);

    k_setup<<<806, 256, 0, stream>>>(dstv, deg, rank, W1, W2, W3, wpk, bt, bnd);
    k_scan1<<<196, 256, 0, stream>>>(deg, dinv, rp, bs);
    k_scan23<<<196, 256, 0, stream>>>(rp, bs, deg, col, hsT);
    k_scatter_xcd<<<((NE + 1023) / 1024) * 8, 256, 0, stream>>>(srcv, dstv, rank, rp, col);

    const dim3 gG((NN + 127) / 128, 2);   // 391 x 2
    k_gemm_mfma<1><<<gG, 256, 0, stream>>>(x, wpk, dinv, hsT);
    k_agg<1, 0><<<12500, 256, 0, stream>>>(hsT, col, rp, dinv, b1, hsA);
    k_gemm_mfma<0><<<gG, 256, 0, stream>>>(hsA, wpk + 32768, dinv, hsT);
    k_agg<1, 0><<<12500, 256, 0, stream>>>(hsT, col, rp, dinv, b2, hsA);
    k_gemm_mfma<0><<<gG, 256, 0, stream>>>(hsA, wpk + 65536, dinv, hsT);
    k_agg<0, 1><<<12500, 256, 0, stream>>>(hsT, col, rp, dinv, b3, F);

    k_pool_seg<<<NG * PCH, 256, 0, stream>>>(F, bnd, pool);
    k_final<<<(NG * DD) / 256, 256, 0, stream>>>(pool, bnd, out);
}